// Round 3
// baseline (218.626 us; speedup 1.0000x reference)
//
#include <hip/hip_runtime.h>
#include <math.h>

#define DD 768
#define NN 64
#define SS 512
#define BB 4
#define PF 8

__device__ __forceinline__ float sigmf(float v) { return 1.0f / (1.0f + expf(-v)); }

// ---- DPP full-wave (64-lane) sum; result valid in lane 63 ----
template <int CTRL>
__device__ __forceinline__ float dppadd(float v) {
    int s = __builtin_amdgcn_update_dpp(0, __float_as_int(v), CTRL, 0xF, 0xF, true);
    return v + __int_as_float(s);
}
__device__ __forceinline__ float wave_sum63(float v) {
    v = dppadd<0x111>(v);  // row_shr:1
    v = dppadd<0x112>(v);  // row_shr:2
    v = dppadd<0x114>(v);  // row_shr:4
    v = dppadd<0x118>(v);  // row_shr:8
    v = dppadd<0x142>(v);  // row_bcast:15
    v = dppadd<0x143>(v);  // row_bcast:31
    return v;              // lane 63 holds the full 64-lane sum
}

// ---- prep: Bw_s = sigmoid(Braw) elementwise ([N][D] native layout); gamma_s ----
__global__ __launch_bounds__(256) void prep_kernel(const float* __restrict__ Braw,
                                                   const float* __restrict__ graw,
                                                   float* __restrict__ Bw_s,
                                                   float* __restrict__ gamma_s) {
    int i = blockIdx.x * 256 + threadIdx.x;
    if (i < DD * NN) Bw_s[i] = sigmf(Braw[i]);
    if (i < DD) gamma_s[i] = sigmf(graw[i]);
}

// ---- transpose x[b][t][d] -> xT[b][d][t] (64x64 LDS tiles) ----
__global__ __launch_bounds__(256) void xpose_kernel(const float* __restrict__ x,
                                                    float* __restrict__ xT) {
    __shared__ float tile[64][65];
    int bidx = blockIdx.x;            // 4 * 8 * 12 = 384
    int b  = bidx / 96;
    int r  = bidx - b * 96;
    int t0 = (r / 12) * 64;
    int d0 = (r % 12) * 64;
    int tx = threadIdx.x & 63;
    int tq = threadIdx.x >> 6;        // 0..3
#pragma unroll
    for (int i = 0; i < 16; ++i) {
        int t = tq + i * 4;
        tile[t][tx] = x[((size_t)b * SS + t0 + t) * DD + d0 + tx];
    }
    __syncthreads();
#pragma unroll
    for (int i = 0; i < 16; ++i) {
        int dl = tq + i * 4;
        xT[((size_t)b * DD + d0 + dl) * SS + t0 + tx] = tile[tx][dl];
    }
}

// ---- phase 1: inp[r][n] = sum_d x[r][d] * Bw_s[n][d]; 4-buffer pipeline ----
__global__ __launch_bounds__(256) void inp_kernel(const float* __restrict__ x,
                                                  const float* __restrict__ Bw_s,
                                                  float* __restrict__ inp) {
    int wid  = (blockIdx.x * 256 + threadIdx.x) >> 6;  // row 0..2047
    int lane = threadIdx.x & 63;
    const float4* xr4 = (const float4*)(x + (size_t)wid * DD);
    const float4* br4 = (const float4*)(Bw_s + (size_t)lane * DD);

    float4 Ab0, Ab1, Ab2, Ab3, Ax0, Ax1, Ax2, Ax3;
    float4 Bb0, Bb1, Bb2, Bb3, Bx0, Bx1, Bx2, Bx3;
    float4 Cb0, Cb1, Cb2, Cb3, Cx0, Cx1, Cx2, Cx3;
    float4 Db0, Db1, Db2, Db3, Dx0, Dx1, Dx2, Dx3;

#define IPREF(P, C0)                                                       \
    {                                                                      \
        int cc_ = ((C0) < 48) ? (C0) : 0;                                  \
        P##b0 = br4[cc_ * 4 + 0]; P##b1 = br4[cc_ * 4 + 1];                \
        P##b2 = br4[cc_ * 4 + 2]; P##b3 = br4[cc_ * 4 + 3];                \
        P##x0 = xr4[cc_ * 4 + 0]; P##x1 = xr4[cc_ * 4 + 1];                \
        P##x2 = xr4[cc_ * 4 + 2]; P##x3 = xr4[cc_ * 4 + 3];                \
    }
#define IFMA4(BX, XX)                          \
    acc0 = fmaf(XX.x, BX.x, acc0);             \
    acc1 = fmaf(XX.y, BX.y, acc1);             \
    acc2 = fmaf(XX.z, BX.z, acc2);             \
    acc3 = fmaf(XX.w, BX.w, acc3);
#define ICOMP(P)                               \
    IFMA4(P##b0, P##x0) IFMA4(P##b1, P##x1)    \
    IFMA4(P##b2, P##x2) IFMA4(P##b3, P##x3)

    IPREF(A, 0) IPREF(B, 1) IPREF(C, 2) IPREF(D, 3)

    float acc0 = 0.f, acc1 = 0.f, acc2 = 0.f, acc3 = 0.f;
    for (int c = 0; c < 48; c += 4) {
        ICOMP(A) IPREF(A, c + 4)
        ICOMP(B) IPREF(B, c + 5)
        ICOMP(C) IPREF(C, c + 6)
        ICOMP(D) IPREF(D, c + 7)
    }
    inp[wid * NN + lane] = (acc0 + acc1) + (acc2 + acc3);
}

// ---- phase 2: per-(b,d) wave scan over t; xT + 4-buffer deep pipeline ----
__global__ __launch_bounds__(256) void scan_kernel(const float* __restrict__ xT,
                                                   const float* __restrict__ Araw,
                                                   const float* __restrict__ Craw,
                                                   const float* __restrict__ inp,
                                                   float* __restrict__ Y,
                                                   float* __restrict__ hfin) {
    int wid  = (blockIdx.x * 256 + threadIdx.x) >> 6;  // 0..3071
    int lane = threadIdx.x & 63;                       // n
    int b = wid / DD;
    int d = wid - b * DD;

    float a = sigmf(Araw[d * NN + lane]);
    float c = sigmf(Craw[d * NN + lane]);

    const float*  ip_ptr = inp + (b * SS) * NN + lane;
    const float4* xt4    = (const float4*)(xT + ((size_t)b * DD + d) * SS);
    float*        y_ptr  = Y + (b * SS) * DD + d;

    float ip0[PF], ip1[PF], ip2[PF], ip3[PF];
    float4 xa0, xb0, xa1, xb1, xa2, xb2, xa3, xb3;
    float h = 0.f;

#define PREF(IP, XA, XB, T0)                                               \
    {                                                                      \
        int tt_ = ((T0) < SS) ? (T0) : 0;                                  \
        _Pragma("unroll")                                                  \
        for (int i_ = 0; i_ < PF; ++i_) IP[i_] = ip_ptr[(tt_ + i_) * NN];  \
        XA = xt4[(tt_ >> 2) + 0];                                          \
        XB = xt4[(tt_ >> 2) + 1];                                          \
    }
#define COMP(IP, XA, XB, T0)                                               \
    {                                                                      \
        const float xs_[8] = {XA.x, XA.y, XA.z, XA.w,                      \
                              XB.x, XB.y, XB.z, XB.w};                     \
        _Pragma("unroll")                                                  \
        for (int i_ = 0; i_ < PF; ++i_) {                                  \
            h = __builtin_amdgcn_fmed3f(fmaf(h, a, IP[i_] * xs_[i_]), 0.f, 1.f); \
            float v_ = wave_sum63(h * c);                                  \
            if (lane == 63) y_ptr[((T0) + i_) * DD] = v_;                  \
        }                                                                  \
    }

    PREF(ip0, xa0, xb0, 0)
    PREF(ip1, xa1, xb1, PF)
    PREF(ip2, xa2, xb2, 2 * PF)
    PREF(ip3, xa3, xb3, 3 * PF)

    for (int t0 = 0; t0 < SS; t0 += 4 * PF) {
        COMP(ip0, xa0, xb0, t0)
        PREF(ip0, xa0, xb0, t0 + 4 * PF)
        COMP(ip1, xa1, xb1, t0 + PF)
        PREF(ip1, xa1, xb1, t0 + 5 * PF)
        COMP(ip2, xa2, xb2, t0 + 2 * PF)
        PREF(ip2, xa2, xb2, t0 + 6 * PF)
        COMP(ip3, xa3, xb3, t0 + 3 * PF)
        PREF(ip3, xa3, xb3, t0 + 7 * PF)
    }
    hfin[(size_t)wid * NN + lane] = h;
}

// ---- fallback scan (no xT; strided x reads) for small workspaces ----
__global__ __launch_bounds__(256) void scan_fb_kernel(const float* __restrict__ x,
                                                      const float* __restrict__ Araw,
                                                      const float* __restrict__ Craw,
                                                      const float* __restrict__ inp,
                                                      float* __restrict__ Y,
                                                      float* __restrict__ hfin) {
    int wid  = (blockIdx.x * 256 + threadIdx.x) >> 6;
    int lane = threadIdx.x & 63;
    int b = wid / DD;
    int d = wid - b * DD;

    float a = sigmf(Araw[d * NN + lane]);
    float c = sigmf(Craw[d * NN + lane]);

    const float* ip_ptr = inp + (b * SS) * NN + lane;
    const float* x_ptr  = x   + (b * SS) * DD + d;
    float*       y_ptr  = Y   + (b * SS) * DD + d;

    float cip[PF], cxv[PF], nip[PF], nxv[PF];
#pragma unroll
    for (int i = 0; i < PF; ++i) {
        cip[i] = ip_ptr[i * NN];
        cxv[i] = x_ptr[i * DD];
    }
    float h = 0.f;
    for (int t0 = 0; t0 < SS; t0 += PF) {
        int tn = t0 + PF;
        if (tn >= SS) tn = SS - PF;
#pragma unroll
        for (int i = 0; i < PF; ++i) {
            nip[i] = ip_ptr[(tn + i) * NN];
            nxv[i] = x_ptr[(tn + i) * DD];
        }
#pragma unroll
        for (int i = 0; i < PF; ++i) {
            h = __builtin_amdgcn_fmed3f(fmaf(h, a, cip[i] * cxv[i]), 0.f, 1.f);
            float v = wave_sum63(h * c);
            if (lane == 63) y_ptr[(t0 + i) * DD] = v;
        }
#pragma unroll
        for (int i = 0; i < PF; ++i) { cip[i] = nip[i]; cxv[i] = nxv[i]; }
    }
    hfin[(size_t)wid * NN + lane] = h;
}

// ---- phase 3: in-place layernorm + gamma + residual + clip (float4) ----
__global__ __launch_bounds__(256) void ln_kernel(const float* __restrict__ x,
                                                 const float* __restrict__ gamma_s,
                                                 float* __restrict__ out) {
    int wid  = (blockIdx.x * 256 + threadIdx.x) >> 6;  // row 0..2047
    int lane = threadIdx.x & 63;
    float*       yr = out + (size_t)wid * DD;
    const float* xr = x   + (size_t)wid * DD;

    float4 y0 = ((const float4*)yr)[lane * 3 + 0];
    float4 y1 = ((const float4*)yr)[lane * 3 + 1];
    float4 y2 = ((const float4*)yr)[lane * 3 + 2];

    float s = ((y0.x + y0.y) + (y0.z + y0.w)) + ((y1.x + y1.y) + (y1.z + y1.w)) +
              ((y2.x + y2.y) + (y2.z + y2.w));
#pragma unroll
    for (int off = 32; off; off >>= 1) s += __shfl_xor(s, off, 64);
    float mu = s * (1.f / 768.f);

    float q = 0.f;
#define QACC(v)                 \
    {                           \
        float d0_ = (v) - mu;   \
        q = fmaf(d0_, d0_, q);  \
    }
    QACC(y0.x) QACC(y0.y) QACC(y0.z) QACC(y0.w)
    QACC(y1.x) QACC(y1.y) QACC(y1.z) QACC(y1.w)
    QACC(y2.x) QACC(y2.y) QACC(y2.z) QACC(y2.w)
#pragma unroll
    for (int off = 32; off; off >>= 1) q += __shfl_xor(q, off, 64);
    float inv = rsqrtf(q * (1.f / 768.f) + 1e-5f);

    float4 g0 = ((const float4*)gamma_s)[lane * 3 + 0];
    float4 g1 = ((const float4*)gamma_s)[lane * 3 + 1];
    float4 g2 = ((const float4*)gamma_s)[lane * 3 + 2];
    float4 x0 = ((const float4*)xr)[lane * 3 + 0];
    float4 x1 = ((const float4*)xr)[lane * 3 + 1];
    float4 x2 = ((const float4*)xr)[lane * 3 + 2];

#define FIN(yv, gv, xv) __builtin_amdgcn_fmed3f(fmaf((yv - mu) * inv, gv, xv), 0.f, 1.f)
    float4 o0, o1, o2;
    o0.x = FIN(y0.x, g0.x, x0.x); o0.y = FIN(y0.y, g0.y, x0.y);
    o0.z = FIN(y0.z, g0.z, x0.z); o0.w = FIN(y0.w, g0.w, x0.w);
    o1.x = FIN(y1.x, g1.x, x1.x); o1.y = FIN(y1.y, g1.y, x1.y);
    o1.z = FIN(y1.z, g1.z, x1.z); o1.w = FIN(y1.w, g1.w, x1.w);
    o2.x = FIN(y2.x, g2.x, x2.x); o2.y = FIN(y2.y, g2.y, x2.y);
    o2.z = FIN(y2.z, g2.z, x2.z); o2.w = FIN(y2.w, g2.w, x2.w);

    ((float4*)yr)[lane * 3 + 0] = o0;
    ((float4*)yr)[lane * 3 + 1] = o1;
    ((float4*)yr)[lane * 3 + 2] = o2;
}

extern "C" void kernel_launch(void* const* d_in, const int* in_sizes, int n_in,
                              void* d_out, int out_size, void* d_ws, size_t ws_size,
                              hipStream_t stream) {
    const float* x    = (const float*)d_in[0];  // [B,S,D]
    const float* Araw = (const float*)d_in[1];  // [D,N]
    const float* Braw = (const float*)d_in[2];  // [N,D]
    const float* Craw = (const float*)d_in[3];  // [D,N]
    const float* graw = (const float*)d_in[4];  // [D]

    float* out  = (float*)d_out;                // [B,S,D] then [B,D,N]
    float* hfin = out + (size_t)BB * SS * DD;

    float* ws      = (float*)d_ws;
    float* Bw_s    = ws;                                   // N*D   = 49152
    float* gamma_s = ws + DD * NN;                         // D     = 768
    float* inp     = ws + DD * NN + DD;                    // B*S*N = 131072
    float* xT      = ws + DD * NN + DD + BB * SS * NN;     // B*D*S = 1572864

    size_t need = (size_t)(DD * NN + DD + (size_t)BB * SS * NN + (size_t)BB * SS * DD) * sizeof(float);

    prep_kernel<<<(DD * NN + 255) / 256, 256, 0, stream>>>(Braw, graw, Bw_s, gamma_s);
    inp_kernel<<<(BB * SS * NN) / 256, 256, 0, stream>>>(x, Bw_s, inp);
    if (ws_size >= need) {
        xpose_kernel<<<BB * (SS / 64) * (DD / 64), 256, 0, stream>>>(x, xT);
        scan_kernel<<<(BB * DD * NN) / 256, 256, 0, stream>>>(xT, Araw, Craw, inp, out, hfin);
    } else {
        scan_fb_kernel<<<(BB * DD * NN) / 256, 256, 0, stream>>>(x, Araw, Craw, inp, out, hfin);
    }
    ln_kernel<<<(BB * SS * NN) / 256, 256, 0, stream>>>(x, gamma_s, out);
}

// Round 4
// 98.918 us; speedup vs baseline: 2.2102x; 2.2102x over previous
//
#include <hip/hip_runtime.h>
#include <math.h>

#define DD 768
#define NN 64
#define SS 512
#define BB 4
#define PF 8

__device__ __forceinline__ float sigmf(float v) { return 1.0f / (1.0f + expf(-v)); }

// ---- DPP full-wave (64-lane) sum; result valid in lane 63 ----
template <int CTRL>
__device__ __forceinline__ float dppadd(float v) {
    int s = __builtin_amdgcn_update_dpp(0, __float_as_int(v), CTRL, 0xF, 0xF, true);
    return v + __int_as_float(s);
}
__device__ __forceinline__ float wave_sum63(float v) {
    v = dppadd<0x111>(v);  // row_shr:1
    v = dppadd<0x112>(v);  // row_shr:2
    v = dppadd<0x114>(v);  // row_shr:4
    v = dppadd<0x118>(v);  // row_shr:8
    v = dppadd<0x142>(v);  // row_bcast:15
    v = dppadd<0x143>(v);  // row_bcast:31
    return v;              // lane 63 holds the full 64-lane sum
}

// ---- prep: BwT[d][n] = sigmoid(Braw[n][d]) via LDS tile (coalesced both sides);
//      gamma_s = sigmoid(graw). 12 blocks, block handles d-tile of 64. ----
__global__ __launch_bounds__(256) void prep_kernel(const float* __restrict__ Braw,
                                                   const float* __restrict__ graw,
                                                   float* __restrict__ BwT,
                                                   float* __restrict__ gamma_s) {
    __shared__ float tile[64][65];
    int d0 = blockIdx.x * 64;
    int tx = threadIdx.x & 63;
    int tq = threadIdx.x >> 6;  // 0..3
#pragma unroll
    for (int i = 0; i < 16; ++i) {
        int n = tq + i * 4;
        tile[n][tx] = sigmf(Braw[n * DD + d0 + tx]);  // coalesced read over d
    }
    __syncthreads();
#pragma unroll
    for (int i = 0; i < 16; ++i) {
        int dl = tq + i * 4;
        BwT[(d0 + dl) * NN + tx] = tile[tx][dl];      // coalesced write over n
    }
    int gi = blockIdx.x * 256 + threadIdx.x;
    if (gi < DD) gamma_s[gi] = sigmf(graw[gi]);
}

// ---- phase 1: inp[r][n] = sum_d x[r][d] * BwT[d][n] ----
// Wave = row r. lane: g = lane>>4 (d-subgroup), q = lane&15 (n-quad).
// Per iteration i (d = 4i+g): float4 bw = BwT[(4i+g)][4q..4q+3]  (1KB/wave contiguous),
// float xv = x[r][4i+g] (16B broadcast). acc float4 over 4 n's; xor16+xor32 reduce.
__global__ __launch_bounds__(256) void inp_kernel(const float* __restrict__ x,
                                                  const float* __restrict__ BwT,
                                                  float* __restrict__ inp) {
    int wid  = (blockIdx.x * 256 + threadIdx.x) >> 6;  // row 0..2047
    int lane = threadIdx.x & 63;
    int g = lane >> 4;
    int q = lane & 15;
    const float*  xr  = x + (size_t)wid * DD;
    const float4* bw4 = (const float4*)BwT + q;        // element d*16 + q

    float4 Aw0, Aw1, Aw2, Aw3; float Ax0, Ax1, Ax2, Ax3;
    float4 Bw0, Bw1, Bw2, Bw3; float Bx0, Bx1, Bx2, Bx3;
    float4 Cw0, Cw1, Cw2, Cw3; float Cx0, Cx1, Cx2, Cx3;
    float4 Dw0, Dw1, Dw2, Dw3; float Dx0, Dx1, Dx2, Dx3;

    // group c covers d = 16c .. 16c+15; j-th slot: d = 16c + 4j + g
#define IPREF(P, C0)                                                     \
    {                                                                    \
        int cc_ = ((C0) < 48) ? (C0) : 0;                                \
        P##w0 = bw4[(16 * cc_ + 0 + g) * 16];                            \
        P##w1 = bw4[(16 * cc_ + 4 + g) * 16];                            \
        P##w2 = bw4[(16 * cc_ + 8 + g) * 16];                            \
        P##w3 = bw4[(16 * cc_ + 12 + g) * 16];                           \
        P##x0 = xr[16 * cc_ + 0 + g];                                    \
        P##x1 = xr[16 * cc_ + 4 + g];                                    \
        P##x2 = xr[16 * cc_ + 8 + g];                                    \
        P##x3 = xr[16 * cc_ + 12 + g];                                   \
    }
#define IFMA(W, X)                       \
    acc.x = fmaf(X, W.x, acc.x);         \
    acc.y = fmaf(X, W.y, acc.y);         \
    acc.z = fmaf(X, W.z, acc.z);         \
    acc.w = fmaf(X, W.w, acc.w);
#define ICOMP(P)                         \
    IFMA(P##w0, P##x0) IFMA(P##w1, P##x1) IFMA(P##w2, P##x2) IFMA(P##w3, P##x3)

    IPREF(A, 0) IPREF(B, 1) IPREF(C, 2) IPREF(D, 3)

    float4 acc = {0.f, 0.f, 0.f, 0.f};
    for (int c = 0; c < 48; c += 4) {
        ICOMP(A) IPREF(A, c + 4)
        ICOMP(B) IPREF(B, c + 5)
        ICOMP(C) IPREF(C, c + 6)
        ICOMP(D) IPREF(D, c + 7)
    }

    // combine the 4 d-subgroups: lanes l, l^16, l^32
#pragma unroll
    for (int off = 16; off <= 32; off <<= 1) {
        acc.x += __shfl_xor(acc.x, off, 64);
        acc.y += __shfl_xor(acc.y, off, 64);
        acc.z += __shfl_xor(acc.z, off, 64);
        acc.w += __shfl_xor(acc.w, off, 64);
    }
    if (lane < 16) ((float4*)(inp + (size_t)wid * NN))[q] = acc;
}

// ---- transpose x[b][t][d] -> xT[b][d][t] (64x64 LDS tiles) ----
__global__ __launch_bounds__(256) void xpose_kernel(const float* __restrict__ x,
                                                    float* __restrict__ xT) {
    __shared__ float tile[64][65];
    int bidx = blockIdx.x;            // 4 * 8 * 12 = 384
    int b  = bidx / 96;
    int r  = bidx - b * 96;
    int t0 = (r / 12) * 64;
    int d0 = (r % 12) * 64;
    int tx = threadIdx.x & 63;
    int tq = threadIdx.x >> 6;        // 0..3
#pragma unroll
    for (int i = 0; i < 16; ++i) {
        int t = tq + i * 4;
        tile[t][tx] = x[((size_t)b * SS + t0 + t) * DD + d0 + tx];
    }
    __syncthreads();
#pragma unroll
    for (int i = 0; i < 16; ++i) {
        int dl = tq + i * 4;
        xT[((size_t)b * DD + d0 + dl) * SS + t0 + tx] = tile[tx][dl];
    }
}

// ---- phase 2: per-(b,d) wave scan over t; xT + 4-buffer deep pipeline ----
__global__ __launch_bounds__(256) void scan_kernel(const float* __restrict__ xT,
                                                   const float* __restrict__ Araw,
                                                   const float* __restrict__ Craw,
                                                   const float* __restrict__ inp,
                                                   float* __restrict__ Y,
                                                   float* __restrict__ hfin) {
    int wid  = (blockIdx.x * 256 + threadIdx.x) >> 6;  // 0..3071
    int lane = threadIdx.x & 63;                       // n
    int b = wid / DD;
    int d = wid - b * DD;

    float a = sigmf(Araw[d * NN + lane]);
    float c = sigmf(Craw[d * NN + lane]);

    const float*  ip_ptr = inp + (b * SS) * NN + lane;
    const float4* xt4    = (const float4*)(xT + ((size_t)b * DD + d) * SS);
    float*        y_ptr  = Y + (b * SS) * DD + d;

    float ip0[PF], ip1[PF], ip2[PF], ip3[PF];
    float4 xa0, xb0, xa1, xb1, xa2, xb2, xa3, xb3;
    float h = 0.f;

#define PREF(IP, XA, XB, T0)                                               \
    {                                                                      \
        int tt_ = ((T0) < SS) ? (T0) : 0;                                  \
        _Pragma("unroll")                                                  \
        for (int i_ = 0; i_ < PF; ++i_) IP[i_] = ip_ptr[(tt_ + i_) * NN];  \
        XA = xt4[(tt_ >> 2) + 0];                                          \
        XB = xt4[(tt_ >> 2) + 1];                                          \
    }
#define COMP(IP, XA, XB, T0)                                               \
    {                                                                      \
        const float xs_[8] = {XA.x, XA.y, XA.z, XA.w,                      \
                              XB.x, XB.y, XB.z, XB.w};                     \
        _Pragma("unroll")                                                  \
        for (int i_ = 0; i_ < PF; ++i_) {                                  \
            h = __builtin_amdgcn_fmed3f(fmaf(h, a, IP[i_] * xs_[i_]), 0.f, 1.f); \
            float v_ = wave_sum63(h * c);                                  \
            if (lane == 63) y_ptr[((T0) + i_) * DD] = v_;                  \
        }                                                                  \
    }

    PREF(ip0, xa0, xb0, 0)
    PREF(ip1, xa1, xb1, PF)
    PREF(ip2, xa2, xb2, 2 * PF)
    PREF(ip3, xa3, xb3, 3 * PF)

    for (int t0 = 0; t0 < SS; t0 += 4 * PF) {
        COMP(ip0, xa0, xb0, t0)
        PREF(ip0, xa0, xb0, t0 + 4 * PF)
        COMP(ip1, xa1, xb1, t0 + PF)
        PREF(ip1, xa1, xb1, t0 + 5 * PF)
        COMP(ip2, xa2, xb2, t0 + 2 * PF)
        PREF(ip2, xa2, xb2, t0 + 6 * PF)
        COMP(ip3, xa3, xb3, t0 + 3 * PF)
        PREF(ip3, xa3, xb3, t0 + 7 * PF)
    }
    hfin[(size_t)wid * NN + lane] = h;
}

// ---- fallback scan (no xT; strided x reads) for small workspaces ----
__global__ __launch_bounds__(256) void scan_fb_kernel(const float* __restrict__ x,
                                                      const float* __restrict__ Araw,
                                                      const float* __restrict__ Craw,
                                                      const float* __restrict__ inp,
                                                      float* __restrict__ Y,
                                                      float* __restrict__ hfin) {
    int wid  = (blockIdx.x * 256 + threadIdx.x) >> 6;
    int lane = threadIdx.x & 63;
    int b = wid / DD;
    int d = wid - b * DD;

    float a = sigmf(Araw[d * NN + lane]);
    float c = sigmf(Craw[d * NN + lane]);

    const float* ip_ptr = inp + (b * SS) * NN + lane;
    const float* x_ptr  = x   + (b * SS) * DD + d;
    float*       y_ptr  = Y   + (b * SS) * DD + d;

    float cip[PF], cxv[PF], nip[PF], nxv[PF];
#pragma unroll
    for (int i = 0; i < PF; ++i) {
        cip[i] = ip_ptr[i * NN];
        cxv[i] = x_ptr[i * DD];
    }
    float h = 0.f;
    for (int t0 = 0; t0 < SS; t0 += PF) {
        int tn = t0 + PF;
        if (tn >= SS) tn = SS - PF;
#pragma unroll
        for (int i = 0; i < PF; ++i) {
            nip[i] = ip_ptr[(tn + i) * NN];
            nxv[i] = x_ptr[(tn + i) * DD];
        }
#pragma unroll
        for (int i = 0; i < PF; ++i) {
            h = __builtin_amdgcn_fmed3f(fmaf(h, a, cip[i] * cxv[i]), 0.f, 1.f);
            float v = wave_sum63(h * c);
            if (lane == 63) y_ptr[(t0 + i) * DD] = v;
        }
#pragma unroll
        for (int i = 0; i < PF; ++i) { cip[i] = nip[i]; cxv[i] = nxv[i]; }
    }
    hfin[(size_t)wid * NN + lane] = h;
}

// ---- phase 3: in-place layernorm + gamma + residual + clip (float4) ----
__global__ __launch_bounds__(256) void ln_kernel(const float* __restrict__ x,
                                                 const float* __restrict__ gamma_s,
                                                 float* __restrict__ out) {
    int wid  = (blockIdx.x * 256 + threadIdx.x) >> 6;  // row 0..2047
    int lane = threadIdx.x & 63;
    float*       yr = out + (size_t)wid * DD;
    const float* xr = x   + (size_t)wid * DD;

    float4 y0 = ((const float4*)yr)[lane * 3 + 0];
    float4 y1 = ((const float4*)yr)[lane * 3 + 1];
    float4 y2 = ((const float4*)yr)[lane * 3 + 2];

    float s = ((y0.x + y0.y) + (y0.z + y0.w)) + ((y1.x + y1.y) + (y1.z + y1.w)) +
              ((y2.x + y2.y) + (y2.z + y2.w));
#pragma unroll
    for (int off = 32; off; off >>= 1) s += __shfl_xor(s, off, 64);
    float mu = s * (1.f / 768.f);

    float q = 0.f;
#define QACC(v)                 \
    {                           \
        float d0_ = (v) - mu;   \
        q = fmaf(d0_, d0_, q);  \
    }
    QACC(y0.x) QACC(y0.y) QACC(y0.z) QACC(y0.w)
    QACC(y1.x) QACC(y1.y) QACC(y1.z) QACC(y1.w)
    QACC(y2.x) QACC(y2.y) QACC(y2.z) QACC(y2.w)
#pragma unroll
    for (int off = 32; off; off >>= 1) q += __shfl_xor(q, off, 64);
    float inv = rsqrtf(q * (1.f / 768.f) + 1e-5f);

    float4 g0 = ((const float4*)gamma_s)[lane * 3 + 0];
    float4 g1 = ((const float4*)gamma_s)[lane * 3 + 1];
    float4 g2 = ((const float4*)gamma_s)[lane * 3 + 2];
    float4 x0 = ((const float4*)xr)[lane * 3 + 0];
    float4 x1 = ((const float4*)xr)[lane * 3 + 1];
    float4 x2 = ((const float4*)xr)[lane * 3 + 2];

#define FIN(yv, gv, xv) __builtin_amdgcn_fmed3f(fmaf((yv - mu) * inv, gv, xv), 0.f, 1.f)
    float4 o0, o1, o2;
    o0.x = FIN(y0.x, g0.x, x0.x); o0.y = FIN(y0.y, g0.y, x0.y);
    o0.z = FIN(y0.z, g0.z, x0.z); o0.w = FIN(y0.w, g0.w, x0.w);
    o1.x = FIN(y1.x, g1.x, x1.x); o1.y = FIN(y1.y, g1.y, x1.y);
    o1.z = FIN(y1.z, g1.z, x1.z); o1.w = FIN(y1.w, g1.w, x1.w);
    o2.x = FIN(y2.x, g2.x, x2.x); o2.y = FIN(y2.y, g2.y, x2.y);
    o2.z = FIN(y2.z, g2.z, x2.z); o2.w = FIN(y2.w, g2.w, x2.w);

    ((float4*)yr)[lane * 3 + 0] = o0;
    ((float4*)yr)[lane * 3 + 1] = o1;
    ((float4*)yr)[lane * 3 + 2] = o2;
}

extern "C" void kernel_launch(void* const* d_in, const int* in_sizes, int n_in,
                              void* d_out, int out_size, void* d_ws, size_t ws_size,
                              hipStream_t stream) {
    const float* x    = (const float*)d_in[0];  // [B,S,D]
    const float* Araw = (const float*)d_in[1];  // [D,N]
    const float* Braw = (const float*)d_in[2];  // [N,D]
    const float* Craw = (const float*)d_in[3];  // [D,N]
    const float* graw = (const float*)d_in[4];  // [D]

    float* out  = (float*)d_out;                // [B,S,D] then [B,D,N]
    float* hfin = out + (size_t)BB * SS * DD;

    float* ws      = (float*)d_ws;
    float* BwT     = ws;                                   // D*N   = 49152
    float* gamma_s = ws + DD * NN;                         // D     = 768
    float* inp     = ws + DD * NN + DD;                    // B*S*N = 131072
    float* xT      = ws + DD * NN + DD + BB * SS * NN;     // B*D*S = 1572864

    size_t need = (size_t)(DD * NN + DD + (size_t)BB * SS * NN + (size_t)BB * SS * DD) * sizeof(float);

    prep_kernel<<<DD / 64, 256, 0, stream>>>(Braw, graw, BwT, gamma_s);
    inp_kernel<<<(BB * SS * NN) / 256, 256, 0, stream>>>(x, BwT, inp);
    if (ws_size >= need) {
        xpose_kernel<<<BB * (SS / 64) * (DD / 64), 256, 0, stream>>>(x, xT);
        scan_kernel<<<(BB * DD * NN) / 256, 256, 0, stream>>>(xT, Araw, Craw, inp, out, hfin);
    } else {
        scan_fb_kernel<<<(BB * DD * NN) / 256, 256, 0, stream>>>(x, Araw, Craw, inp, out, hfin);
    }
    ln_kernel<<<(BB * SS * NN) / 256, 256, 0, stream>>>(x, gamma_s, out);
}